// Round 2
// baseline (7383.857 us; speedup 1.0000x reference)
//
#include <hip/hip_runtime.h>
#include <math.h>

#define DEVINL __device__ __forceinline__

// ---------- cross-lane primitives (all VALU-rate, no LDS/DS) ----------

template<int CTRL>
DEVINL float dppf(float x) {
  // DPP-selected copy of x: result_lane = x from lane given by CTRL pattern.
  return __int_as_float(__builtin_amdgcn_update_dpp(
      0, __float_as_int(x), CTRL, 0xF, 0xF, true));
}
// ctrl codes: quad_perm[1,0,3,2]=0xB1 (xor1), quad_perm[2,3,0,1]=0x4E (xor2),
// row_half_mirror=0x141 (xor7), row_mirror=0x140 (xor15)

DEVINL float sum16(float x) {  // x + (x from lane^16); direction-agnostic
  float a, b;
  asm volatile("v_mov_b32 %0, %2\n\t"
               "v_mov_b32 %1, %2\n\t"
               "s_nop 1\n\t"
               "v_permlane16_swap_b32 %0, %1"
               : "=&v"(a), "=&v"(b)
               : "v"(x));
  return a + b;
}
DEVINL float sum32(float x) {  // x + (x from lane^32)
  float a, b;
  asm volatile("v_mov_b32 %0, %2\n\t"
               "v_mov_b32 %1, %2\n\t"
               "s_nop 1\n\t"
               "v_permlane32_swap_b32 %0, %1"
               : "=&v"(a), "=&v"(b)
               : "v"(x));
  return a + b;
}
DEVINL float partner16(float x) { return sum16(x) - x; }  // value at lane^16
DEVINL float partner32(float x) { return sum32(x) - x; }  // value at lane^32

DEVINL float ftanh(float x) {
  float ax = __builtin_fabsf(x);
  float e  = __expf(-2.0f * ax);                       // in (0,1], no overflow
  float r  = (1.0f - e) * __builtin_amdgcn_rcpf(1.0f + e);
  return __builtin_copysignf(r, x);
}

// reduce-scatter within each 16-lane row over 16 slots; mask order 1,2,7,15.
// Requires products laid out as p[i] = M[phi4(i)^ (lane&15)][k_lane]*v.
// After this, p[0] = (row partial) for output j = lane&15.
DEVINL void rs16(float (&p)[16]) {
#pragma unroll
  for (int i = 0; i < 8; ++i) p[i] += dppf<0xB1>(p[i + 8]);
#pragma unroll
  for (int i = 0; i < 4; ++i) p[i] += dppf<0x4E>(p[i + 4]);
#pragma unroll
  for (int i = 0; i < 2; ++i) p[i] += dppf<0x141>(p[i + 2]);
  p[0] += dppf<0x140>(p[1]);
}

// ---------- vf: scale * tanh(tanh(w2 @ tanh(w1 @ tanh(w0@[t,y]+b0) + b1) + b2)) ----------

struct VFW {
  float w0r[16];  // w0[(phi4(i)^jl)][1+lane]
  float w1r[16];  // w1[(phi4(i)^jl)][jl]
  float w2r[16];  // w2[lane][jl ^ c4(i)]
  float w0c0, b0l, b1l, b2l, scale;
};

DEVINL float vf_eval(const VFW& W, float t, float y) {
  // layer 0: 16x64 part, reduce over all 64 lanes, output j=lane&15 (R16)
  float p[16];
#pragma unroll
  for (int i = 0; i < 16; ++i) p[i] = W.w0r[i] * y;
  rs16(p);
  float s0 = sum32(sum16(p[0]));
  float z0 = ftanh(fmaf(t, W.w0c0, s0 + W.b0l));
  // layer 1: 16x16 within-row (rows are replicas)
  float q[16];
#pragma unroll
  for (int i = 0; i < 16; ++i) q[i] = W.w1r[i] * z0;
  rs16(q);
  float z1 = ftanh(q[0] + W.b1l);
  // layer 2: 64x16 — allgather z1 within row (span order c4), then dot
  float g[16];
  g[0] = z1;
  g[1] = dppf<0xB1>(g[0]);
  g[2] = dppf<0x4E>(g[0]);
  g[3] = dppf<0x4E>(g[1]);
#pragma unroll
  for (int i = 0; i < 4; ++i) g[4 + i] = dppf<0x141>(g[i]);
#pragma unroll
  for (int i = 0; i < 8; ++i) g[8 + i] = dppf<0x140>(g[i]);
  float acc = W.b2l;
#pragma unroll
  for (int i = 0; i < 16; ++i) acc = fmaf(W.w2r[i], g[i], acc);
  return W.scale * ftanh(ftanh(acc));
}

// ---------- Tsit5 coefficients ----------
#define A31f (-0.008480655492356989f)
#define A32f ( 0.335480655492357f)
#define A41f ( 2.8971530571054935f)
#define A42f (-6.359448489975075f)
#define A43f ( 4.3622954328695815f)
#define A51f ( 5.325864828439257f)
#define A52f (-11.748883564062828f)
#define A53f ( 7.4955393428898365f)
#define A54f (-0.09249506636175525f)
#define A61f ( 5.86145544294642f)
#define A62f (-12.92096931784711f)
#define A63f ( 8.159367898576159f)
#define A64f (-0.071584973281401f)
#define A65f (-0.028269050394068383f)
#define B1f  ( 0.09646076681806523f)
#define B2f  ( 0.01f)
#define B3f  ( 0.4798896504144996f)
#define B4f  ( 1.379008574103742f)
#define B5f  (-3.290069515436081f)
#define B6f  ( 2.324710524099774f)
#define C2f  ( 0.161f)
#define C3f  ( 0.327f)
#define C4f  ( 0.9f)
#define C5f  ( 0.9800255409045097f)

__global__ void __launch_bounds__(64, 1)
ode_rnn_scan(const float* __restrict__ ts, const float* __restrict__ obs,
             const float* __restrict__ scalep,
             const float* __restrict__ w0, const float* __restrict__ b0,
             const float* __restrict__ w1, const float* __restrict__ b1,
             const float* __restrict__ w2, const float* __restrict__ b2,
             const float* __restrict__ Wh, const float* __restrict__ Wx,
             const float* __restrict__ bx,
             const float* __restrict__ ow0, const float* __restrict__ ob0,
             const float* __restrict__ ow1, const float* __restrict__ ob1,
             const float* __restrict__ ow2, const float* __restrict__ ob2,
             float* __restrict__ out, int B, int N)
{
  const int b  = blockIdx.x;
  if (b >= B) return;
  const int l  = threadIdx.x;   // 0..63
  const int jl = l & 15;

  const int phi4[16] = {0,15,7,8, 2,13,5,10, 1,14,6,9, 3,12,4,11};
  const int c4t[16]  = {0,1,2,3, 7,6,5,4, 15,14,13,12, 8,9,10,11};

  // ---- permuted weight preload into registers ----
  VFW W;
#pragma unroll
  for (int i = 0; i < 16; ++i) W.w0r[i] = w0[(phi4[i] ^ jl) * 65 + 1 + l];
#pragma unroll
  for (int i = 0; i < 16; ++i) W.w1r[i] = w1[(phi4[i] ^ jl) * 16 + jl];
#pragma unroll
  for (int i = 0; i < 16; ++i) W.w2r[i] = w2[l * 16 + (jl ^ c4t[i])];
  W.w0c0 = w0[jl * 65];
  W.b0l  = b0[jl];
  W.b1l  = b1[jl];
  W.b2l  = b2[l];
  W.scale = scalep[0];

  float Whr[64];
#pragma unroll
  for (int i = 0; i < 64; ++i) {
    int ph = ((i>>5)&1)*1 ^ ((i>>4)&1)*2 ^ ((i>>3)&1)*7
           ^ ((i>>2)&1)*15 ^ ((i>>1)&1)*16 ^ (i&1)*32;
    Whr[i] = Wh[(ph ^ l) * 64 + l];
  }
  float Wxr[32];
#pragma unroll
  for (int i = 0; i < 32; ++i) {
    int ph = ((i>>4)&1)*1 ^ ((i>>3)&1)*2 ^ ((i>>2)&1)*7
           ^ ((i>>1)&1)*15 ^ (i&1)*16;
    Wxr[i] = Wx[(ph ^ l) * 32 + (l & 31)];
  }
  const float bxl = bx[l];

  const float* tsb  = ts  + (size_t)b * N;
  const float* obsb = obs + (size_t)b * N * 32;

  float h  = 0.0f;
  float t1 = tsb[0];
  float t0 = t1;
  float x_cur = obsb[l & 31];

#pragma unroll 1
  for (int n = 0; n < N; ++n) {
    // prefetch next step's inputs (hidden under ~16k cycles of ODE work)
    const int np1 = (n + 1 < N) ? n + 1 : n;
    float t_next = tsb[np1];
    float x_next = obsb[(size_t)np1 * 32 + (l & 31)];

    const float dt = (t1 - t0) * 0.125f;

    // ---- fixed-step Tsit5, 8 sub-steps ----
    float y = h;
#pragma unroll 1
    for (int st = 0; st < 8; ++st) {
      const float tb = fmaf((float)st, dt, t0);
      float k1 = vf_eval(W, tb, y);
      float k2 = vf_eval(W, fmaf(C2f, dt, tb), fmaf(dt * C2f, k1, y));
      float k3 = vf_eval(W, fmaf(C3f, dt, tb),
                         fmaf(dt, fmaf(A32f, k2, A31f * k1), y));
      float k4 = vf_eval(W, fmaf(C4f, dt, tb),
                         fmaf(dt, fmaf(A43f, k3, fmaf(A42f, k2, A41f * k1)), y));
      float k5 = vf_eval(W, fmaf(C5f, dt, tb),
                         fmaf(dt, fmaf(A54f, k4, fmaf(A53f, k3,
                              fmaf(A52f, k2, A51f * k1))), y));
      float k6 = vf_eval(W, tb + dt,
                         fmaf(dt, fmaf(A65f, k5, fmaf(A64f, k4, fmaf(A63f, k3,
                              fmaf(A62f, k2, A61f * k1)))), y));
      y = fmaf(dt, fmaf(B6f, k6, fmaf(B5f, k5, fmaf(B4f, k4, fmaf(B3f, k3,
               fmaf(B2f, k2, B1f * k1))))), y);
    }

    // ---- obs projection: out[l] = sum_{i<32} Wx[l][i] x[i] ----
    float q[32];
#pragma unroll
    for (int i = 0; i < 32; ++i) q[i] = Wxr[i] * x_cur;
#pragma unroll
    for (int i = 0; i < 16; ++i) q[i] += dppf<0xB1>(q[i + 16]);
#pragma unroll
    for (int i = 0; i < 8; ++i)  q[i] += dppf<0x4E>(q[i + 8]);
#pragma unroll
    for (int i = 0; i < 4; ++i)  q[i] += dppf<0x141>(q[i + 4]);
#pragma unroll
    for (int i = 0; i < 2; ++i)  q[i] += dppf<0x140>(q[i + 2]);
    float xm = q[0] + partner16(q[1]) + bxl;

    // ---- recurrent matvec: out[l] = sum_i Wh[l][i] y[i] ----
    float r[64];
#pragma unroll
    for (int i = 0; i < 64; ++i) r[i] = Whr[i] * y;
#pragma unroll
    for (int i = 0; i < 32; ++i) r[i] += dppf<0xB1>(r[i + 32]);
#pragma unroll
    for (int i = 0; i < 16; ++i) r[i] += dppf<0x4E>(r[i + 16]);
#pragma unroll
    for (int i = 0; i < 8; ++i)  r[i] += dppf<0x141>(r[i + 8]);
#pragma unroll
    for (int i = 0; i < 4; ++i)  r[i] += dppf<0x140>(r[i + 4]);
    r[0] += partner16(r[2]);
    r[1] += partner16(r[3]);
    r[0] += partner32(r[1]);

    h = ftanh(r[0] + xm);

    t0 = t1; t1 = t_next; x_cur = x_next;
  }

  // ---- h_final ----
  out[(size_t)B * 8 + (size_t)b * 64 + l] = h;

  // ---- output MLP: relu(ow0@h+ob0) -> relu(ow1@.+ob1) -> ow2@.+ob2 ----
  float p[16];
#pragma unroll
  for (int i = 0; i < 16; ++i) p[i] = ow0[(phi4[i] ^ jl) * 64 + l] * h;
  rs16(p);
  float v1 = fmaxf(sum32(sum16(p[0])) + ob0[jl], 0.0f);
#pragma unroll
  for (int i = 0; i < 16; ++i) p[i] = ow1[(phi4[i] ^ jl) * 16 + jl] * v1;
  rs16(p);
  float v2 = fmaxf(p[0] + ob1[jl], 0.0f);

  float g[16];
  g[0] = v2;
  g[1] = dppf<0xB1>(g[0]);
  g[2] = dppf<0x4E>(g[0]);
  g[3] = dppf<0x4E>(g[1]);
#pragma unroll
  for (int i = 0; i < 4; ++i) g[4 + i] = dppf<0x141>(g[i]);
#pragma unroll
  for (int i = 0; i < 8; ++i) g[8 + i] = dppf<0x140>(g[i]);
  float acc = ob2[l & 7];
#pragma unroll
  for (int i = 0; i < 16; ++i)
    acc = fmaf(ow2[(l & 7) * 16 + (jl ^ c4t[i])], g[i], acc);
  if (l < 8) out[(size_t)b * 8 + l] = acc;
}

extern "C" void kernel_launch(void* const* d_in, const int* in_sizes, int n_in,
                              void* d_out, int out_size, void* d_ws, size_t ws_size,
                              hipStream_t stream) {
  const float* ts     = (const float*)d_in[0];
  const float* obs    = (const float*)d_in[1];
  const float* scalep = (const float*)d_in[2];
  const float* w0  = (const float*)d_in[3];
  const float* b0  = (const float*)d_in[4];
  const float* w1  = (const float*)d_in[5];
  const float* b1  = (const float*)d_in[6];
  const float* w2  = (const float*)d_in[7];
  const float* b2  = (const float*)d_in[8];
  const float* Wh  = (const float*)d_in[9];
  const float* Wx  = (const float*)d_in[10];
  const float* bx  = (const float*)d_in[11];
  const float* ow0 = (const float*)d_in[12];
  const float* ob0 = (const float*)d_in[13];
  const float* ow1 = (const float*)d_in[14];
  const float* ob1 = (const float*)d_in[15];
  const float* ow2 = (const float*)d_in[16];
  const float* ob2 = (const float*)d_in[17];
  float* out = (float*)d_out;

  const int B = out_size / 72;        // 8 + 64 outputs per sequence
  const int N = in_sizes[0] / B;      // ts is [B, N]

  hipLaunchKernelGGL(ode_rnn_scan, dim3(B), dim3(64), 0, stream,
                     ts, obs, scalep, w0, b0, w1, b1, w2, b2,
                     Wh, Wx, bx, ow0, ob0, ow1, ob1, ow2, ob2,
                     out, B, N);
}